// Round 7
// baseline (3970.654 us; speedup 1.0000x reference)
//
#include <hip/hip_runtime.h>

namespace {

constexpr int kB = 512, kD = 64, kP = 16, kT = 500, kH = 128;
constexpr int kRows = 16;            // batch rows per wave (one MFMA tile)
constexpr int kBlocks = kB / kRows;  // 32 blocks, 1 wave each, no intra-step barriers
constexpr int kThreads = 64;

// Dynamic LDS: 64 weight fragments (64 lanes x 8 shorts = 1KB each) + biases.
// W1 (hi+lo) and W2-hi live in AGPRs this round (320 regs); LDS keeps:
//   0..15  W0z-hi (T*2+kt)
//  16..31  W0z-lo
//  32..39  W0p-hi (T)
//  40..47  W0p-lo (T)
//  48..63  W2-lo  (T*4+kt)
constexpr int kFS = 512;                     // shorts per fragment
constexpr int kNFrag = 64;
constexpr int kBiasOff = kNFrag * kFS * 2;   // 65536 bytes
constexpr int kDynLds = kBiasOff + 320 * 4;  // + b0[128], b1[128], b2[64] = 66816

typedef __attribute__((ext_vector_type(8))) short short8;
typedef __attribute__((ext_vector_type(4))) float float4v;

__device__ __forceinline__ float bf2f(unsigned short u) {
  union { unsigned int i; float f; } v;
  v.i = ((unsigned int)u) << 16;
  return v.f;
}
__device__ __forceinline__ unsigned short f2bf(float f) {  // RNE
  union { float f; unsigned int i; } v;
  v.f = f;
  return (unsigned short)((v.i + 0x7FFFu + ((v.i >> 16) & 1u)) >> 16);
}
__device__ __forceinline__ void split_bf(float x, unsigned short& hi, unsigned short& lo) {
  hi = f2bf(x);
  lo = f2bf(x - bf2f(hi));
}
#if __has_builtin(__builtin_amdgcn_cvt_pk_bf16_f32)
__device__ __forceinline__ unsigned int pk_bf16(float a, float b) {
  auto v = __builtin_amdgcn_cvt_pk_bf16_f32(a, b);
  unsigned int u;
  __builtin_memcpy(&u, &v, 4);
  return u;
}
#else
__device__ __forceinline__ unsigned int pk_bf16(float a, float b) {
  return (unsigned int)f2bf(a) | ((unsigned int)f2bf(b) << 16);
}
#endif
// split a pair (a,b) into packed bf16 hi word + lo word
__device__ __forceinline__ void sp2(float a, float b, unsigned int& hw, unsigned int& lw) {
  unsigned int uh = pk_bf16(a, b);
  float ah, bh;
  { unsigned int t1 = uh << 16; __builtin_memcpy(&ah, &t1, 4); }
  { unsigned int t2 = uh & 0xFFFF0000u; __builtin_memcpy(&bh, &t2, 4); }
  hw = uh;
  lw = pk_bf16(a - ah, b - bh);
}
__device__ __forceinline__ short8 mk8(unsigned int a, unsigned int b, unsigned int c,
                                      unsigned int d) {
  union { unsigned int w[4]; short8 s; } u;
  u.w[0] = a; u.w[1] = b; u.w[2] = c; u.w[3] = d;
  return u.s;
}
__device__ __forceinline__ float fast_tanh(float x) {
  // 1 - 2/(e^{2x}+1): exact saturation both ends, no NaN.
  float e = __builtin_amdgcn_exp2f(x * 2.885390081777927f);  // 2*log2(e)
  return 1.0f - 2.0f * __builtin_amdgcn_rcpf(e + 1.0f);
}

#define MFMA(a, b, c) __builtin_amdgcn_mfma_f32_16x16x32_bf16((a), (b), (c), 0, 0, 0)

// Transposed-MFMA formulation: A = W^T tile, B = activations^T (batch row =
// lane&15), D[hidden][row]. Tile T covers hidden cols
// n(T,m) = 32*(T>>1) + 8*(m>>2) + 4*(T&1) + (m&3).
// Producer D-cell (T=2kt+(j>=4), reg=j&3) of layer L sits on EXACTLY the lane
// that needs it as B-frag element (kt, j) of layer L+1 -> handoff is pure
// register repacking. No activation LDS round-trip, no __syncthreads in the
// 500-step loop. Round 6 (all weights LDS) ran clean (no spill, VGPR=116) but
// read-latency-bound at ~304 ds_reads/step with no register headroom. This
// round: W1-hi/W1-lo/W2-hi (80 frags = 320 regs) pinned into AGPRs -> L1 is
// pure-register, reads drop to ~144/step, ~190 VGPRs left for read batching.
__global__ __launch_bounds__(kThreads, 1) void node_kernel(
    const float* __restrict__ xg, const float* __restrict__ pg,
    const float* __restrict__ w0g, const float* __restrict__ b0g,
    const float* __restrict__ w1g, const float* __restrict__ b1g,
    const float* __restrict__ w2g, const float* __restrict__ b2g,
    float* __restrict__ outg) {
  extern __shared__ char dynraw[];
  short* dynS = (short*)dynraw;
  float* bflds = (float*)(dynraw + kBiasOff);

  const int lane = threadIdx.x & 63;
  const int l15 = lane & 15;
  const int q = lane >> 4;
  const int lane8 = lane * 8;
  const int brow = blockIdx.x * kRows;

  // ---- persistent AGPR weight fragments: W1 hi/lo, W2 hi ----
  short8 w1h[8][4], w1l[8][4], w2h[4][4];

  // ---- stage W0z/W0p/W2-lo fragments into LDS; W1, W2-hi into registers ----
#pragma unroll
  for (int T = 0; T < 8; ++T) {
    const int nW = 32 * (T >> 1) + 8 * (l15 >> 2) + 4 * (T & 1) + (l15 & 3);
#pragma unroll
    for (int kt = 0; kt < 2; ++kt) {  // W0 state part (k 0..63)
      short8 vh, vl;
#pragma unroll
      for (int j = 0; j < 8; ++j) {
        unsigned short hi, lo;
        split_bf(w0g[(kt * 32 + q * 8 + j) * kH + nW], hi, lo);
        vh[j] = (short)hi; vl[j] = (short)lo;
      }
      *(short8*)&dynS[(T * 2 + kt) * kFS + lane8] = vh;
      *(short8*)&dynS[(16 + T * 2 + kt) * kFS + lane8] = vl;
    }
    {  // W0 p part (k 64..79, zero-padded to 96)
      short8 vh, vl;
#pragma unroll
      for (int j = 0; j < 8; ++j) {
        int k = 64 + q * 8 + j;
        unsigned short hi = 0, lo = 0;
        if (k < 80) split_bf(w0g[k * kH + nW], hi, lo);
        vh[j] = (short)hi; vl[j] = (short)lo;
      }
      *(short8*)&dynS[(32 + T) * kFS + lane8] = vh;
      *(short8*)&dynS[(40 + T) * kFS + lane8] = vl;
    }
#pragma unroll
    for (int kt = 0; kt < 4; ++kt) {  // W1 -> registers (hi and lo)
      short8 vh, vl;
#pragma unroll
      for (int j = 0; j < 8; ++j) {
        unsigned short hi, lo;
        split_bf(w1g[(kt * 32 + q * 8 + j) * kH + nW], hi, lo);
        vh[j] = (short)hi; vl[j] = (short)lo;
      }
      w1h[T][kt] = vh;
      w1l[T][kt] = vl;
    }
  }
#pragma unroll
  for (int T = 0; T < 4; ++T) {  // W2 (64 output cols): hi -> regs, lo -> LDS
    const int nW = 32 * (T >> 1) + 8 * (l15 >> 2) + 4 * (T & 1) + (l15 & 3);
#pragma unroll
    for (int kt = 0; kt < 4; ++kt) {
      short8 vh, vl;
#pragma unroll
      for (int j = 0; j < 8; ++j) {
        unsigned short hi, lo;
        split_bf(w2g[(kt * 32 + q * 8 + j) * kD + nW], hi, lo);
        vh[j] = (short)hi; vl[j] = (short)lo;
      }
      w2h[T][kt] = vh;
      *(short8*)&dynS[(48 + T * 4 + kt) * kFS + lane8] = vl;
    }
  }
  // ---- pin the persistent weight frags into the AGPR class (zero-instr) ----
  // All uses are MFMA A-operands (AV-class on gfx950) -> they stay in AGPRs,
  // keeping arch-VGPR demand low (round 6 measured 116 without them).
#pragma unroll
  for (int T = 0; T < 8; ++T) {
    asm("" : "+a"(w1h[T][0]), "+a"(w1h[T][1]), "+a"(w1h[T][2]), "+a"(w1h[T][3]));
    asm("" : "+a"(w1l[T][0]), "+a"(w1l[T][1]), "+a"(w1l[T][2]), "+a"(w1l[T][3]));
  }
#pragma unroll
  for (int T = 0; T < 4; ++T)
    asm("" : "+a"(w2h[T][0]), "+a"(w2h[T][1]), "+a"(w2h[T][2]), "+a"(w2h[T][3]));

  // biases
  for (int i = lane; i < 128; i += 64) {
    bflds[i] = b0g[i];
    bflds[128 + i] = b1g[i];
  }
  bflds[256 + lane] = b2g[lane];

  // ---- lane-local fp32 state: lane(q,l15) holds rows l15, d = n(T, q*4+r) ----
  float stv[16];
#pragma unroll
  for (int T = 0; T < 4; ++T)
#pragma unroll
    for (int r = 0; r < 4; ++r)
      stv[T * 4 + r] =
          xg[((size_t)(brow + l15) * kD + (32 * (T >> 1) + 8 * q + 4 * (T & 1) + r)) * kT];

  const float* prow = pg + ((size_t)(brow + l15) * kP + q * 8) * kT;  // valid q<2
  float pcur[8];
#pragma unroll
  for (int j = 0; j < 8; ++j) pcur[j] = 0.f;
  if (q < 2) {
#pragma unroll
    for (int j = 0; j < 8; ++j) pcur[j] = prow[j * kT];
  }
  float* orow = outg + ((size_t)(brow + l15) * kD + q * 8) * kT;

  __syncthreads();  // LDS weight images ready (single wave: also a waitcnt fence)

  const int bq = 8 * q;

  // Obscured LDS offsets: asm pins make them opaque per t-iteration and per
  // Heun-eval so the store-free weight ds_reads can't be hoisted/CSE'd into
  // long-lived registers (round 2/3 spill mechanism). Base stays AS3 ->
  // ds_read_b128 with immediate offsets (region < 64KB).
  unsigned wo1 = 0;             // frag region: 0..63
  unsigned wob = kBiasOff / 2;  // biases (float region, short-indexed base)

#define RD(rel) (*(const short8*)&dynS[wo1 + (rel) * kFS + lane8])
#define BIAS4(i) (*(const float4v*)&((const float*)&dynS[wob])[(i)])
#define BIDX(T) (32 * ((T) >> 1) + bq + 4 * ((T)&1))

  short8 zfh[2], zfl[2];  // state B-fragments (hi/lo split)
  auto buildz = [&](const float* v) {
#pragma unroll
    for (int kt = 0; kt < 2; ++kt) {
      unsigned int hw[4], lw[4];
#pragma unroll
      for (int u = 0; u < 4; ++u) {
        int Ta = 2 * kt + (u >> 1), bb = u & 1;
        sp2(v[Ta * 4 + 2 * bb], v[Ta * 4 + 2 * bb + 1], hw[u], lw[u]);
      }
      zfh[kt] = mk8(hw[0], hw[1], hw[2], hw[3]);
      zfl[kt] = mk8(lw[0], lw[1], lw[2], lw[3]);
    }
  };
  buildz(stv);

  for (int t = 0; t < kT; ++t) {
    asm("" : "+v"(wo1), "+v"(wob));  // t-scope pin
    // p B-fragments for this step (zero on lanes q>=2 via pcur=0)
    short8 zph, zpl;
    {
      unsigned int hw[4], lw[4];
#pragma unroll
      for (int u = 0; u < 4; ++u) sp2(pcur[2 * u], pcur[2 * u + 1], hw[u], lw[u]);
      zph = mk8(hw[0], hw[1], hw[2], hw[3]);
      zpl = mk8(lw[0], lw[1], lw[2], lw[3]);
    }
    // step-invariant p-term (+bias0), cached across both Heun evals
    float4v psum[8];
#pragma unroll
    for (int T = 0; T < 8; ++T) {
      float4v s = BIAS4(BIDX(T));
      short8 wph = RD(32 + T);
      s = MFMA(wph, zph, s);
      s = MFMA(wph, zpl, s);
      s = MFMA(RD(40 + T), zph, s);
      psum[T] = s;
    }
    // prefetch p(t+1); latency hides under the evals
    float pnx[8];
#pragma unroll
    for (int j = 0; j < 8; ++j) pnx[j] = 0.f;
    if (q < 2 && t + 1 < kT) {
#pragma unroll
      for (int j = 0; j < 8; ++j) pnx[j] = prow[j * kT + (t + 1)];
    }

    float d1v[16];
#pragma unroll
    for (int ev = 0; ev < 2; ++ev) {
      asm("" : "+v"(wo1), "+v"(wob));  // eval-scope pin (blocks cross-eval CSE)
      // ---- L0: D = W0^T z^T (+psum) ----
      short8 h0f[4];
#pragma unroll
      for (int kt = 0; kt < 4; ++kt) {
        unsigned int w[4];
#pragma unroll
        for (int hf = 0; hf < 2; ++hf) {
          const int T = 2 * kt + hf;
          float4v ac = psum[T];
          short8 wh0 = RD(T * 2), wh1 = RD(T * 2 + 1);
          ac = MFMA(wh0, zfh[0], ac);
          ac = MFMA(wh1, zfh[1], ac);
          ac = MFMA(wh0, zfl[0], ac);
          ac = MFMA(wh1, zfl[1], ac);
          ac = MFMA(RD(16 + T * 2), zfh[0], ac);
          ac = MFMA(RD(17 + T * 2), zfh[1], ac);
          w[hf * 2 + 0] = pk_bf16(fast_tanh(ac[0]), fast_tanh(ac[1]));
          w[hf * 2 + 1] = pk_bf16(fast_tanh(ac[2]), fast_tanh(ac[3]));
        }
        h0f[kt] = mk8(w[0], w[1], w[2], w[3]);
      }
      // ---- L1: pure-AGPR weights, no LDS reads in the deepest chain ----
      short8 h1f[4];
#pragma unroll
      for (int kt = 0; kt < 4; ++kt) {
        unsigned int w[4];
#pragma unroll
        for (int hf = 0; hf < 2; ++hf) {
          const int T = 2 * kt + hf;
          float4v ac = BIAS4(128 + BIDX(T));
          ac = MFMA(w1h[T][0], h0f[0], ac);
          ac = MFMA(w1h[T][1], h0f[1], ac);
          ac = MFMA(w1h[T][2], h0f[2], ac);
          ac = MFMA(w1h[T][3], h0f[3], ac);
          ac = MFMA(w1l[T][0], h0f[0], ac);
          ac = MFMA(w1l[T][1], h0f[1], ac);
          ac = MFMA(w1l[T][2], h0f[2], ac);
          ac = MFMA(w1l[T][3], h0f[3], ac);
          w[hf * 2 + 0] = pk_bf16(fast_tanh(ac[0]), fast_tanh(ac[1]));
          w[hf * 2 + 1] = pk_bf16(fast_tanh(ac[2]), fast_tanh(ac[3]));
        }
        h1f[kt] = mk8(w[0], w[1], w[2], w[3]);
      }
      // ---- L2: hi from AGPR, lo from LDS ----
      float a2[16];
#pragma unroll
      for (int T = 0; T < 4; ++T) {
        float4v ac = BIAS4(256 + BIDX(T));
        ac = MFMA(w2h[T][0], h1f[0], ac);
        ac = MFMA(w2h[T][1], h1f[1], ac);
        ac = MFMA(w2h[T][2], h1f[2], ac);
        ac = MFMA(w2h[T][3], h1f[3], ac);
        ac = MFMA(RD(48 + T * 4 + 0), h1f[0], ac);
        ac = MFMA(RD(48 + T * 4 + 1), h1f[1], ac);
        ac = MFMA(RD(48 + T * 4 + 2), h1f[2], ac);
        ac = MFMA(RD(48 + T * 4 + 3), h1f[3], ac);
#pragma unroll
        for (int r = 0; r < 4; ++r) a2[T * 4 + r] = ac[r];
      }
      // ---- Heun update (all lane-local) ----
      if (ev == 0) {
        float xiv[16];  // transient: dead after buildz
#pragma unroll
        for (int i2 = 0; i2 < 16; ++i2) {
          d1v[i2] = a2[i2];
          xiv[i2] = stv[i2] + a2[i2];  // dt = 1
        }
        buildz(xiv);
      } else {
#pragma unroll
        for (int T = 0; T < 4; ++T)
#pragma unroll
          for (int r = 0; r < 4; ++r)  // emit PREVIOUS state
            orow[((T >> 1) * 32 + (T & 1) * 4 + r) * kT + t] = stv[T * 4 + r];
#pragma unroll
        for (int i2 = 0; i2 < 16; ++i2) stv[i2] = stv[i2] + 0.5f * (a2[i2] + d1v[i2]);
        buildz(stv);
      }
    }
#pragma unroll
    for (int j = 0; j < 8; ++j) pcur[j] = pnx[j];
  }
#undef RD
#undef BIAS4
#undef BIDX
}

}  // namespace

extern "C" void kernel_launch(void* const* d_in, const int* in_sizes, int n_in,
                              void* d_out, int out_size, void* d_ws, size_t ws_size,
                              hipStream_t stream) {
  const float* xg = (const float*)d_in[0];   // x [512,64,500]
  const float* pg = (const float*)d_in[1];   // p [512,16,500]
  // d_in[2] = i_ext (unused by Simple_MLP)
  const float* w0g = (const float*)d_in[3];  // W0 [80,128]
  const float* b0g = (const float*)d_in[4];  // b0 [128]
  const float* w1g = (const float*)d_in[5];  // W1 [128,128]
  const float* b1g = (const float*)d_in[6];  // b1 [128]
  const float* w2g = (const float*)d_in[7];  // W2 [128,64]
  const float* b2g = (const float*)d_in[8];  // b2 [64]
  float* outg = (float*)d_out;               // [512,64,500] fp32

  static bool attr_done = false;
  if (!attr_done) {
    hipFuncSetAttribute(reinterpret_cast<const void*>(node_kernel),
                        hipFuncAttributeMaxDynamicSharedMemorySize, kDynLds);
    attr_done = true;
  }
  hipLaunchKernelGGL(node_kernel, dim3(kBlocks), dim3(kThreads), kDynLds, stream,
                     xg, pg, w0g, b0g, w1g, b1g, w2g, b2g, outg);
}

// Round 9
// 3485.518 us; speedup vs baseline: 1.1392x; 1.1392x over previous
//
#include <hip/hip_runtime.h>

namespace {

constexpr int kB = 512, kD = 64, kP = 16, kT = 500, kH = 128;
constexpr int kRows = 16;            // batch rows per wave (one MFMA tile)
constexpr int kBlocks = kB / kRows;  // 32 blocks, 1 wave each, no intra-step barriers
constexpr int kThreads = 64;

// Dynamic LDS: ALL 144 split-weight fragments (64 lanes x 8 shorts = 1KB each)
// + bias arrays. Linear lane*16B layout -> conflict-free ds_read_b128.
// Abs frag map:
//   0..31   W1-hi  (T*4+kt)          region0 rel T*4+kt
//   32..63  W1-lo  (32+T*4+kt)       region0 rel 32+T*4+kt
//   64..79  W0z-hi (64+T*2+kt)       region1 rel T*2+kt
//   80..95  W0z-lo                   region1 rel 16+T*2+kt
//   96..103 W0p-hi                   region1 rel 32+T
//  104..111 W0p-lo                   region1 rel 40+T
//  112..127 W2-hi                    region1 rel 48+T*4+kt
//  128..143 W2-lo                    region2 rel T*4+kt
constexpr int kFS = 512;                     // shorts per fragment
constexpr int kNFrag = 144;
constexpr int kBiasOff = kNFrag * kFS * 2;   // 147456 bytes
constexpr int kDynLds = kBiasOff + 320 * 4;  // + b0[128], b1[128], b2[64] = 148736

typedef __attribute__((ext_vector_type(8))) short short8;
typedef __attribute__((ext_vector_type(4))) float float4v;

__device__ __forceinline__ float bf2f(unsigned short u) {
  union { unsigned int i; float f; } v;
  v.i = ((unsigned int)u) << 16;
  return v.f;
}
__device__ __forceinline__ unsigned short f2bf(float f) {  // RNE
  union { float f; unsigned int i; } v;
  v.f = f;
  return (unsigned short)((v.i + 0x7FFFu + ((v.i >> 16) & 1u)) >> 16);
}
__device__ __forceinline__ void split_bf(float x, unsigned short& hi, unsigned short& lo) {
  hi = f2bf(x);
  lo = f2bf(x - bf2f(hi));
}
#if __has_builtin(__builtin_amdgcn_cvt_pk_bf16_f32)
__device__ __forceinline__ unsigned int pk_bf16(float a, float b) {
  auto v = __builtin_amdgcn_cvt_pk_bf16_f32(a, b);
  unsigned int u;
  __builtin_memcpy(&u, &v, 4);
  return u;
}
#else
__device__ __forceinline__ unsigned int pk_bf16(float a, float b) {
  return (unsigned int)f2bf(a) | ((unsigned int)f2bf(b) << 16);
}
#endif
// split a pair (a,b) into packed bf16 hi word + lo word
__device__ __forceinline__ void sp2(float a, float b, unsigned int& hw, unsigned int& lw) {
  unsigned int uh = pk_bf16(a, b);
  float ah, bh;
  { unsigned int t1 = uh << 16; __builtin_memcpy(&ah, &t1, 4); }
  { unsigned int t2 = uh & 0xFFFF0000u; __builtin_memcpy(&bh, &t2, 4); }
  hw = uh;
  lw = pk_bf16(a - ah, b - bh);
}
__device__ __forceinline__ short8 mk8(unsigned int a, unsigned int b, unsigned int c,
                                      unsigned int d) {
  union { unsigned int w[4]; short8 s; } u;
  u.w[0] = a; u.w[1] = b; u.w[2] = c; u.w[3] = d;
  return u.s;
}
__device__ __forceinline__ float fast_tanh(float x) {
  // 1 - 2/(e^{2x}+1): exact saturation both ends, no NaN.
  float e = __builtin_amdgcn_exp2f(x * 2.885390081777927f);  // 2*log2(e)
  return 1.0f - 2.0f * __builtin_amdgcn_rcpf(e + 1.0f);
}

#define MFMA(a, b, c) __builtin_amdgcn_mfma_f32_16x16x32_bf16((a), (b), (c), 0, 0, 0)

// Transposed-MFMA formulation: A = W^T tile (ALL weights in LDS), B =
// activations^T (batch row = lane&15), D[hidden][row]. Tile T covers hidden
// cols n(T,m) = 32*(T>>1) + 8*(m>>2) + 4*(T&1) + (m&3).
// Producer D-cell (T=2kt+(j>=4), reg=j&3) of layer L sits on EXACTLY the lane
// that needs it as B-frag element (kt, j) of layer L+1 -> handoff is pure
// register repacking. No __syncthreads in the 500-step loop.
// Round 6 (this base) ran clean (no spill, VGPR=116, 3512us) but was
// serialized per-tile: exposed LDS latency + single-accumulator MFMA chains
// ~= 15k cy/step. This round: tile-PAIR interleaving with 4 independent
// accumulator chains in flight + double-buffered L0 fragment prefetch ->
// latency hides under issue. Same product set; only fp32 add order changes.
__global__ __launch_bounds__(kThreads, 1) void node_kernel(
    const float* __restrict__ xg, const float* __restrict__ pg,
    const float* __restrict__ w0g, const float* __restrict__ b0g,
    const float* __restrict__ w1g, const float* __restrict__ b1g,
    const float* __restrict__ w2g, const float* __restrict__ b2g,
    float* __restrict__ outg) {
  extern __shared__ char dynraw[];
  short* dynS = (short*)dynraw;
  float* bflds = (float*)(dynraw + kBiasOff);

  const int lane = threadIdx.x & 63;
  const int l15 = lane & 15;
  const int q = lane >> 4;
  const int lane8 = lane * 8;
  const int brow = blockIdx.x * kRows;

  // ---- stage ALL split-weight fragments (hi and lo) into LDS ----
#pragma unroll
  for (int T = 0; T < 8; ++T) {
    const int nW = 32 * (T >> 1) + 8 * (l15 >> 2) + 4 * (T & 1) + (l15 & 3);
#pragma unroll
    for (int kt = 0; kt < 2; ++kt) {  // W0 state part (k 0..63)
      short8 vh, vl;
#pragma unroll
      for (int j = 0; j < 8; ++j) {
        unsigned short hi, lo;
        split_bf(w0g[(kt * 32 + q * 8 + j) * kH + nW], hi, lo);
        vh[j] = (short)hi; vl[j] = (short)lo;
      }
      *(short8*)&dynS[(64 + T * 2 + kt) * kFS + lane8] = vh;
      *(short8*)&dynS[(80 + T * 2 + kt) * kFS + lane8] = vl;
    }
    {  // W0 p part (k 64..79, zero-padded to 96)
      short8 vh, vl;
#pragma unroll
      for (int j = 0; j < 8; ++j) {
        int k = 64 + q * 8 + j;
        unsigned short hi = 0, lo = 0;
        if (k < 80) split_bf(w0g[k * kH + nW], hi, lo);
        vh[j] = (short)hi; vl[j] = (short)lo;
      }
      *(short8*)&dynS[(96 + T) * kFS + lane8] = vh;
      *(short8*)&dynS[(104 + T) * kFS + lane8] = vl;
    }
#pragma unroll
    for (int kt = 0; kt < 4; ++kt) {  // W1
      short8 vh, vl;
#pragma unroll
      for (int j = 0; j < 8; ++j) {
        unsigned short hi, lo;
        split_bf(w1g[(kt * 32 + q * 8 + j) * kH + nW], hi, lo);
        vh[j] = (short)hi; vl[j] = (short)lo;
      }
      *(short8*)&dynS[(T * 4 + kt) * kFS + lane8] = vh;
      *(short8*)&dynS[(32 + T * 4 + kt) * kFS + lane8] = vl;
    }
  }
#pragma unroll
  for (int T = 0; T < 4; ++T) {  // W2 (64 output cols)
    const int nW = 32 * (T >> 1) + 8 * (l15 >> 2) + 4 * (T & 1) + (l15 & 3);
#pragma unroll
    for (int kt = 0; kt < 4; ++kt) {
      short8 vh, vl;
#pragma unroll
      for (int j = 0; j < 8; ++j) {
        unsigned short hi, lo;
        split_bf(w2g[(kt * 32 + q * 8 + j) * kD + nW], hi, lo);
        vh[j] = (short)hi; vl[j] = (short)lo;
      }
      *(short8*)&dynS[(112 + T * 4 + kt) * kFS + lane8] = vh;
      *(short8*)&dynS[(128 + T * 4 + kt) * kFS + lane8] = vl;
    }
  }
  // biases
  for (int i = lane; i < 128; i += 64) {
    bflds[i] = b0g[i];
    bflds[128 + i] = b1g[i];
  }
  bflds[256 + lane] = b2g[lane];

  // ---- lane-local fp32 state: lane(q,l15) holds rows l15, d = n(T, q*4+r) ----
  float stv[16];
#pragma unroll
  for (int T = 0; T < 4; ++T)
#pragma unroll
    for (int r = 0; r < 4; ++r)
      stv[T * 4 + r] =
          xg[((size_t)(brow + l15) * kD + (32 * (T >> 1) + 8 * q + 4 * (T & 1) + r)) * kT];

  const float* prow = pg + ((size_t)(brow + l15) * kP + q * 8) * kT;  // valid q<2
  float pcur[8];
#pragma unroll
  for (int j = 0; j < 8; ++j) pcur[j] = 0.f;
  if (q < 2) {
#pragma unroll
    for (int j = 0; j < 8; ++j) pcur[j] = prow[j * kT];
  }
  float* orow = outg + ((size_t)(brow + l15) * kD + q * 8) * kT;

  __syncthreads();  // LDS weight images ready (single wave: also a waitcnt fence)

  const int bq = 8 * q;
  const float4v Z4 = {0.f, 0.f, 0.f, 0.f};

  // Obscured LDS offsets: asm pins make them opaque per t-iteration and per
  // Heun-eval, so the store-free weight ds_reads can't be hoisted/CSE'd into
  // long-lived registers (round 2/3 spill mechanism). Base stays AS3 ->
  // ds_read_b128 with immediate offsets (each region < 64KB).
  unsigned wo0 = 0;             // region0: frags 0..63   (W1 hi/lo)
  unsigned wo1 = 64u * kFS;     // region1: frags 64..127 (W0z, W0p, W2-hi)
  unsigned wo2 = 128u * kFS;    // region2: frags 128..143 (W2-lo)
  unsigned wob = kBiasOff / 2;  // biases (float region, short-indexed base)

#define RD0(rel) (*(const short8*)&dynS[wo0 + (rel) * kFS + lane8])
#define RD1(rel) (*(const short8*)&dynS[wo1 + (rel) * kFS + lane8])
#define RD2(rel) (*(const short8*)&dynS[wo2 + (rel) * kFS + lane8])
#define BIAS4(i) (*(const float4v*)&((const float*)&dynS[wob])[(i)])
#define BIDX(T) (32 * ((T) >> 1) + bq + 4 * ((T)&1))

  short8 zfh[2], zfl[2];  // state B-fragments (hi/lo split)
  auto buildz = [&](const float* v) {
#pragma unroll
    for (int kt = 0; kt < 2; ++kt) {
      unsigned int hw[4], lw[4];
#pragma unroll
      for (int u = 0; u < 4; ++u) {
        int Ta = 2 * kt + (u >> 1), bb = u & 1;
        sp2(v[Ta * 4 + 2 * bb], v[Ta * 4 + 2 * bb + 1], hw[u], lw[u]);
      }
      zfh[kt] = mk8(hw[0], hw[1], hw[2], hw[3]);
      zfl[kt] = mk8(lw[0], lw[1], lw[2], lw[3]);
    }
  };
  buildz(stv);

  for (int t = 0; t < kT; ++t) {
    asm("" : "+v"(wo0), "+v"(wo1), "+v"(wo2), "+v"(wob));  // t-scope pin
    // p B-fragments for this step (zero on lanes q>=2 via pcur=0)
    short8 zph, zpl;
    {
      unsigned int hw[4], lw[4];
#pragma unroll
      for (int u = 0; u < 4; ++u) sp2(pcur[2 * u], pcur[2 * u + 1], hw[u], lw[u]);
      zph = mk8(hw[0], hw[1], hw[2], hw[3]);
      zpl = mk8(lw[0], lw[1], lw[2], lw[3]);
    }
    // step-invariant p-term (+bias0), cached across both Heun evals.
    // 8 independent accumulators -> already latency-parallel.
    float4v psum[8];
#pragma unroll
    for (int T = 0; T < 8; ++T) {
      float4v s = BIAS4(BIDX(T));
      short8 wph = RD1(32 + T);
      s = MFMA(wph, zph, s);
      s = MFMA(wph, zpl, s);
      s = MFMA(RD1(40 + T), zph, s);
      psum[T] = s;
    }
    // prefetch p(t+1); latency hides under the evals
    float pnx[8];
#pragma unroll
    for (int j = 0; j < 8; ++j) pnx[j] = 0.f;
    if (q < 2 && t + 1 < kT) {
#pragma unroll
      for (int j = 0; j < 8; ++j) pnx[j] = prow[j * kT + (t + 1)];
    }

    float d1v[16];
#pragma unroll
    for (int ev = 0; ev < 2; ++ev) {
      asm("" : "+v"(wo0), "+v"(wo1), "+v"(wo2), "+v"(wob));  // eval-scope pin

      // ---- L0: 4 tile-pairs, double-buffered frag prefetch, 4 chains/pair --
      // Per tile T: products {wh0*zfh0, wh1*zfh1} (chain A, psum-seeded) and
      // {wh0*zfl0, wh1*zfl1, wl0*zfh0, wl1*zfh1} (chain B), A+B at the end.
      short8 h0f[4];
      {
#define L0_LD(p0, p1, p2, p3, p4, p5, p6, p7, kt)                              \
  p0 = RD1(4 * (kt));     p1 = RD1(4 * (kt) + 1);                              \
  p2 = RD1(16 + 4 * (kt)); p3 = RD1(17 + 4 * (kt));                            \
  p4 = RD1(4 * (kt) + 2); p5 = RD1(4 * (kt) + 3);                              \
  p6 = RD1(18 + 4 * (kt)); p7 = RD1(19 + 4 * (kt));
#define L0_CP(p0, p1, p2, p3, p4, p5, p6, p7, kt)                              \
  {                                                                            \
    float4v aA = psum[2 * (kt)], bA = psum[2 * (kt) + 1];                      \
    float4v aB = MFMA(p0, zfl[0], Z4), bB = MFMA(p4, zfl[0], Z4);              \
    aA = MFMA(p0, zfh[0], aA);  bA = MFMA(p4, zfh[0], bA);                     \
    aB = MFMA(p1, zfl[1], aB);  bB = MFMA(p5, zfl[1], bB);                     \
    aA = MFMA(p1, zfh[1], aA);  bA = MFMA(p5, zfh[1], bA);                     \
    aB = MFMA(p2, zfh[0], aB);  bB = MFMA(p6, zfh[0], bB);                     \
    aB = MFMA(p3, zfh[1], aB);  bB = MFMA(p7, zfh[1], bB);                     \
    float4v a = aA + aB, b = bA + bB;                                          \
    h0f[kt] = mk8(pk_bf16(fast_tanh(a[0]), fast_tanh(a[1])),                   \
                  pk_bf16(fast_tanh(a[2]), fast_tanh(a[3])),                   \
                  pk_bf16(fast_tanh(b[0]), fast_tanh(b[1])),                   \
                  pk_bf16(fast_tanh(b[2]), fast_tanh(b[3])));                  \
  }
        short8 a0, a1, a2f, a3, a4, a5, a6, a7;
        short8 b0, b1, b2f, b3, b4, b5, b6, b7;
        L0_LD(a0, a1, a2f, a3, a4, a5, a6, a7, 0)
        L0_LD(b0, b1, b2f, b3, b4, b5, b6, b7, 1)
        L0_CP(a0, a1, a2f, a3, a4, a5, a6, a7, 0)
        L0_LD(a0, a1, a2f, a3, a4, a5, a6, a7, 2)
        L0_CP(b0, b1, b2f, b3, b4, b5, b6, b7, 1)
        L0_LD(b0, b1, b2f, b3, b4, b5, b6, b7, 3)
        L0_CP(a0, a1, a2f, a3, a4, a5, a6, a7, 2)
        L0_CP(b0, b1, b2f, b3, b4, b5, b6, b7, 3)
#undef L0_LD
#undef L0_CP
      }

      // ---- L1: 4 tile-pairs, pair-top batched reads, 4 chains/pair ----
      short8 h1f[4];
#pragma unroll
      for (int kt = 0; kt < 4; ++kt) {
        const int T0 = 2 * kt, T1 = T0 + 1;
        short8 g0 = RD0(4 * T0), g1 = RD0(4 * T0 + 1);
        short8 g2 = RD0(4 * T0 + 2), g3 = RD0(4 * T0 + 3);
        short8 g4 = RD0(32 + 4 * T0), g5 = RD0(32 + 4 * T0 + 1);
        short8 g6 = RD0(32 + 4 * T0 + 2), g7 = RD0(32 + 4 * T0 + 3);
        short8 k0 = RD0(4 * T1), k1 = RD0(4 * T1 + 1);
        short8 k2 = RD0(4 * T1 + 2), k3 = RD0(4 * T1 + 3);
        short8 k4 = RD0(32 + 4 * T1), k5 = RD0(32 + 4 * T1 + 1);
        short8 k6 = RD0(32 + 4 * T1 + 2), k7 = RD0(32 + 4 * T1 + 3);
        float4v aA = BIAS4(128 + BIDX(T0)), bA = BIAS4(128 + BIDX(T1));
        float4v aB = MFMA(g4, h0f[0], Z4), bB = MFMA(k4, h0f[0], Z4);
        aA = MFMA(g0, h0f[0], aA);  bA = MFMA(k0, h0f[0], bA);
        aB = MFMA(g5, h0f[1], aB);  bB = MFMA(k5, h0f[1], bB);
        aA = MFMA(g1, h0f[1], aA);  bA = MFMA(k1, h0f[1], bA);
        aB = MFMA(g6, h0f[2], aB);  bB = MFMA(k6, h0f[2], bB);
        aA = MFMA(g2, h0f[2], aA);  bA = MFMA(k2, h0f[2], bA);
        aB = MFMA(g7, h0f[3], aB);  bB = MFMA(k7, h0f[3], bB);
        aA = MFMA(g3, h0f[3], aA);  bA = MFMA(k3, h0f[3], bA);
        float4v a = aA + aB, b = bA + bB;
        h1f[kt] = mk8(pk_bf16(fast_tanh(a[0]), fast_tanh(a[1])),
                      pk_bf16(fast_tanh(a[2]), fast_tanh(a[3])),
                      pk_bf16(fast_tanh(b[0]), fast_tanh(b[1])),
                      pk_bf16(fast_tanh(b[2]), fast_tanh(b[3])));
      }

      // ---- L2: 2 tile-pairs, same pattern ----
      float a2[16];
#pragma unroll
      for (int kt = 0; kt < 2; ++kt) {
        const int T0 = 2 * kt, T1 = T0 + 1;
        short8 g0 = RD1(48 + 4 * T0), g1 = RD1(48 + 4 * T0 + 1);
        short8 g2 = RD1(48 + 4 * T0 + 2), g3 = RD1(48 + 4 * T0 + 3);
        short8 g4 = RD2(4 * T0), g5 = RD2(4 * T0 + 1);
        short8 g6 = RD2(4 * T0 + 2), g7 = RD2(4 * T0 + 3);
        short8 k0 = RD1(48 + 4 * T1), k1 = RD1(48 + 4 * T1 + 1);
        short8 k2 = RD1(48 + 4 * T1 + 2), k3 = RD1(48 + 4 * T1 + 3);
        short8 k4 = RD2(4 * T1), k5 = RD2(4 * T1 + 1);
        short8 k6 = RD2(4 * T1 + 2), k7 = RD2(4 * T1 + 3);
        float4v aA = BIAS4(256 + BIDX(T0)), bA = BIAS4(256 + BIDX(T1));
        float4v aB = MFMA(g4, h1f[0], Z4), bB = MFMA(k4, h1f[0], Z4);
        aA = MFMA(g0, h1f[0], aA);  bA = MFMA(k0, h1f[0], bA);
        aB = MFMA(g5, h1f[1], aB);  bB = MFMA(k5, h1f[1], bB);
        aA = MFMA(g1, h1f[1], aA);  bA = MFMA(k1, h1f[1], bA);
        aB = MFMA(g6, h1f[2], aB);  bB = MFMA(k6, h1f[2], bB);
        aA = MFMA(g2, h1f[2], aA);  bA = MFMA(k2, h1f[2], bA);
        aB = MFMA(g7, h1f[3], aB);  bB = MFMA(k7, h1f[3], bB);
        aA = MFMA(g3, h1f[3], aA);  bA = MFMA(k3, h1f[3], bA);
        float4v a = aA + aB, b = bA + bB;
#pragma unroll
        for (int r = 0; r < 4; ++r) {
          a2[T0 * 4 + r] = a[r];
          a2[T1 * 4 + r] = b[r];
        }
      }

      // ---- Heun update (all lane-local) ----
      if (ev == 0) {
        float xiv[16];  // transient: dead after buildz
#pragma unroll
        for (int i2 = 0; i2 < 16; ++i2) {
          d1v[i2] = a2[i2];
          xiv[i2] = stv[i2] + a2[i2];  // dt = 1
        }
        buildz(xiv);
      } else {
#pragma unroll
        for (int T = 0; T < 4; ++T)
#pragma unroll
          for (int r = 0; r < 4; ++r)  // emit PREVIOUS state
            orow[((T >> 1) * 32 + (T & 1) * 4 + r) * kT + t] = stv[T * 4 + r];
#pragma unroll
        for (int i2 = 0; i2 < 16; ++i2) stv[i2] = stv[i2] + 0.5f * (a2[i2] + d1v[i2]);
        buildz(stv);
      }
    }
#pragma unroll
    for (int j = 0; j < 8; ++j) pcur[j] = pnx[j];
  }
#undef RD0
#undef RD1
#undef RD2
#undef BIAS4
#undef BIDX
}

}  // namespace

extern "C" void kernel_launch(void* const* d_in, const int* in_sizes, int n_in,
                              void* d_out, int out_size, void* d_ws, size_t ws_size,
                              hipStream_t stream) {
  const float* xg = (const float*)d_in[0];   // x [512,64,500]
  const float* pg = (const float*)d_in[1];   // p [512,16,500]
  // d_in[2] = i_ext (unused by Simple_MLP)
  const float* w0g = (const float*)d_in[3];  // W0 [80,128]
  const float* b0g = (const float*)d_in[4];  // b0 [128]
  const float* w1g = (const float*)d_in[5];  // W1 [128,128]
  const float* b1g = (const float*)d_in[6];  // b1 [128]
  const float* w2g = (const float*)d_in[7];  // W2 [128,64]
  const float* b2g = (const float*)d_in[8];  // b2 [64]
  float* outg = (float*)d_out;               // [512,64,500] fp32

  static bool attr_done = false;
  if (!attr_done) {
    hipFuncSetAttribute(reinterpret_cast<const void*>(node_kernel),
                        hipFuncAttributeMaxDynamicSharedMemorySize, kDynLds);
    attr_done = true;
  }
  hipLaunchKernelGGL(node_kernel, dim3(kBlocks), dim3(kThreads), kDynLds, stream,
                     xg, pg, w0g, b0g, w1g, b1g, w2g, b2g, outg);
}

// Round 10
// 1390.462 us; speedup vs baseline: 2.8556x; 2.5067x over previous
//
#include <hip/hip_runtime.h>

namespace {

constexpr int kB = 512, kD = 64, kP = 16, kT = 500, kH = 128;
constexpr int kRows = 16;            // batch rows per block (MFMA N=16)
constexpr int kBlocks = kB / kRows;  // 32
constexpr int kThreads = 256;        // 4 waves: tiles split across waves

typedef __attribute__((ext_vector_type(8))) short short8;
typedef __attribute__((ext_vector_type(4))) float float4v;
typedef __attribute__((ext_vector_type(2))) unsigned int uint2v;

__device__ __forceinline__ float bf2f(unsigned short u) {
  union { unsigned int i; float f; } v;
  v.i = ((unsigned int)u) << 16;
  return v.f;
}
__device__ __forceinline__ unsigned short f2bf(float f) {  // RNE
  union { float f; unsigned int i; } v;
  v.f = f;
  return (unsigned short)((v.i + 0x7FFFu + ((v.i >> 16) & 1u)) >> 16);
}
__device__ __forceinline__ void split_bf(float x, unsigned short& hi, unsigned short& lo) {
  hi = f2bf(x);
  lo = f2bf(x - bf2f(hi));
}
#if __has_builtin(__builtin_amdgcn_cvt_pk_bf16_f32)
__device__ __forceinline__ unsigned int pk_bf16(float a, float b) {
  auto v = __builtin_amdgcn_cvt_pk_bf16_f32(a, b);
  unsigned int u;
  __builtin_memcpy(&u, &v, 4);
  return u;
}
#else
__device__ __forceinline__ unsigned int pk_bf16(float a, float b) {
  return (unsigned int)f2bf(a) | ((unsigned int)f2bf(b) << 16);
}
#endif
// split pair (a,b) into packed bf16 hi word + lo word
__device__ __forceinline__ void sp2(float a, float b, unsigned int& hw, unsigned int& lw) {
  unsigned int uh = pk_bf16(a, b);
  float ah, bh;
  { unsigned int t1 = uh << 16; __builtin_memcpy(&ah, &t1, 4); }
  { unsigned int t2 = uh & 0xFFFF0000u; __builtin_memcpy(&bh, &t2, 4); }
  hw = uh;
  lw = pk_bf16(a - ah, b - bh);
}
__device__ __forceinline__ short8 mk8(unsigned int a, unsigned int b, unsigned int c,
                                      unsigned int d) {
  union { unsigned int w[4]; short8 s; } u;
  u.w[0] = a; u.w[1] = b; u.w[2] = c; u.w[3] = d;
  return u.s;
}
__device__ __forceinline__ float fast_tanh(float x) {
  float e = __builtin_amdgcn_exp2f(x * 2.885390081777927f);  // 2*log2(e)
  return 1.0f - 2.0f * __builtin_amdgcn_rcpf(e + 1.0f);
}

#define MFMA(a, b, c) __builtin_amdgcn_mfma_f32_16x16x32_bf16((a), (b), (c), 0, 0, 0)

// 4-wave transposed-MFMA hybrid. A = W^T tile (ALL weights in AGPRs: each wave
// holds only ITS tiles' 36 frags = 144 regs, so no spill), B = activations^T
// (batch row = lane&15), D[hidden][row]. Tile T covers hidden cols
// n(T,m) = 32*(T>>1) + 8*(m>>2) + 4*(T&1) + (m&3), m = quad*4+reg.
// Wave w owns L0/L1 tiles {2w, 2w+1} and L2 tile {w}. Inter-layer activations
// exchanged through tiny XOR-swizzled LDS planes addressed by ABSOLUTE
// (row, col) coordinates (no cross-wave lane mapping needed). 6 barriers/step
// like the old 8-wave kernel, but: weights+biases fully register-resident
// (zero weight LDS reads vs 272/step), 4 waves (less skew), swizzle-clean
// planes (old kernel had 16.4M bank conflicts), L2 balanced across waves.
__global__ __launch_bounds__(kThreads, 1) void node_kernel(
    const float* __restrict__ xg, const float* __restrict__ pg,
    const float* __restrict__ w0g, const float* __restrict__ b0g,
    const float* __restrict__ w1g, const float* __restrict__ b1g,
    const float* __restrict__ w2g, const float* __restrict__ b2g,
    float* __restrict__ outg) {
  // Exchange planes (bf16). Row-major, col XOR-swizzled by ((row&7)<<3) in
  // short units (= byte bits [6:4]) so stride-256B/128B column reads spread
  // across banks (2-way max). 12.25 KB total.
  __shared__ __align__(16) unsigned short h0p[16 * 128];
  __shared__ __align__(16) unsigned short h1p[16 * 128];
  __shared__ __align__(16) unsigned short zhp[16 * 64];
  __shared__ __align__(16) unsigned short zlp[16 * 64];

  const int tid = threadIdx.x;
  const int wv = tid >> 6;  // wave 0..3
  const int lane = tid & 63;
  const int l15 = lane & 15;
  const int q = lane >> 4;
  const int brow = blockIdx.x * kRows;
  const int sw = (l15 & 7) << 3;  // plane col swizzle (short units, bits 5:3)

  // ---- per-wave weight fragments -> AGPRs (36 frags = 144 regs) ----
  // wz[u][0..1]=W0z hi kt, [2..3]=lo; wp[u][0]=W0p hi,[1]=lo;
  // w1f[u][0..3]=hi, [4..7]=lo; w2f[0..3]=hi,[4..7]=lo (tile wv).
  short8 wz[2][4], wp[2][2], w1f[2][8], w2f[8];
#pragma unroll
  for (int u = 0; u < 2; ++u) {
    const int T = 2 * wv + u;
    const int nW = 32 * (T >> 1) + 8 * (l15 >> 2) + 4 * (T & 1) + (l15 & 3);
#pragma unroll
    for (int kt = 0; kt < 2; ++kt) {
      short8 vh, vl;
#pragma unroll
      for (int j = 0; j < 8; ++j) {
        unsigned short hi, lo;
        split_bf(w0g[(kt * 32 + q * 8 + j) * kH + nW], hi, lo);
        vh[j] = (short)hi; vl[j] = (short)lo;
      }
      wz[u][kt] = vh; wz[u][2 + kt] = vl;
    }
    {
      short8 vh, vl;
#pragma unroll
      for (int j = 0; j < 8; ++j) {
        int k = 64 + q * 8 + j;
        unsigned short hi = 0, lo = 0;
        if (k < 80) split_bf(w0g[k * kH + nW], hi, lo);
        vh[j] = (short)hi; vl[j] = (short)lo;
      }
      wp[u][0] = vh; wp[u][1] = vl;
    }
#pragma unroll
    for (int kt = 0; kt < 4; ++kt) {
      short8 vh, vl;
#pragma unroll
      for (int j = 0; j < 8; ++j) {
        unsigned short hi, lo;
        split_bf(w1g[(kt * 32 + q * 8 + j) * kH + nW], hi, lo);
        vh[j] = (short)hi; vl[j] = (short)lo;
      }
      w1f[u][kt] = vh; w1f[u][4 + kt] = vl;
    }
  }
  {
    const int nW2 = 32 * (wv >> 1) + 8 * (l15 >> 2) + 4 * (wv & 1) + (l15 & 3);
#pragma unroll
    for (int kt = 0; kt < 4; ++kt) {
      short8 vh, vl;
#pragma unroll
      for (int j = 0; j < 8; ++j) {
        unsigned short hi, lo;
        split_bf(w2g[(kt * 32 + q * 8 + j) * kD + nW2], hi, lo);
        vh[j] = (short)hi; vl[j] = (short)lo;
      }
      w2f[kt] = vh; w2f[4 + kt] = vl;
    }
  }
#pragma unroll
  for (int u = 0; u < 2; ++u) {
    asm("" : "+a"(wz[u][0]), "+a"(wz[u][1]), "+a"(wz[u][2]), "+a"(wz[u][3]));
    asm("" : "+a"(wp[u][0]), "+a"(wp[u][1]));
    asm("" : "+a"(w1f[u][0]), "+a"(w1f[u][1]), "+a"(w1f[u][2]), "+a"(w1f[u][3]));
    asm("" : "+a"(w1f[u][4]), "+a"(w1f[u][5]), "+a"(w1f[u][6]), "+a"(w1f[u][7]));
  }
  asm("" : "+a"(w2f[0]), "+a"(w2f[1]), "+a"(w2f[2]), "+a"(w2f[3]));
  asm("" : "+a"(w2f[4]), "+a"(w2f[5]), "+a"(w2f[6]), "+a"(w2f[7]));

  // ---- biases in registers ----
  const int bqw = 32 * wv + 8 * q;  // L0/L1 tile base col for u=0
  float4v b0v[2] = {*(const float4v*)&b0g[bqw], *(const float4v*)&b0g[bqw + 4]};
  float4v b1v[2] = {*(const float4v*)&b1g[bqw], *(const float4v*)&b1g[bqw + 4]};
  const int n0out = 32 * (wv >> 1) + 8 * q + 4 * (wv & 1);  // L2 tile col base
  float4v b2v = *(const float4v*)&b2g[n0out];

  // ---- lane-local fp32 state: 4 dims (n0out + r), row l15 ----
  float stv[4];
#pragma unroll
  for (int r = 0; r < 4; ++r)
    stv[r] = xg[((size_t)(brow + l15) * kD + n0out + r) * kT];

  const float* prow = pg + ((size_t)(brow + l15) * kP + q * 8) * kT;  // q<2
  float pcur[8];
#pragma unroll
  for (int j = 0; j < 8; ++j) pcur[j] = 0.f;
  if (q < 2) {
#pragma unroll
    for (int j = 0; j < 8; ++j) pcur[j] = prow[j * kT];
  }
  float* orow = outg + ((size_t)(brow + l15) * kD + n0out) * kT;

  // plane addresses
  const int zwi = l15 * 64 + (n0out ^ sw);                  // z write (8B)
  const int hwi0 = l15 * 128 + ((bqw) ^ sw);                // h write u=0 (8B)
  const int hwi1 = l15 * 128 + ((bqw + 4) ^ sw);            // h write u=1
#define RDH(plane, kt) (*(const short8*)&plane[l15 * 128 + ((((kt)*32) + q * 8) ^ sw)])
#define RDZ(plane, kt) (*(const short8*)&plane[l15 * 64 + ((((kt)*32) + q * 8) ^ sw)])

  // ---- init z planes from state ----
  {
    unsigned int hw0, lw0, hw1, lw1;
    sp2(stv[0], stv[1], hw0, lw0);
    sp2(stv[2], stv[3], hw1, lw1);
    *(uint2v*)&zhp[zwi] = (uint2v){hw0, hw1};
    *(uint2v*)&zlp[zwi] = (uint2v){lw0, lw1};
  }
  __syncthreads();

  const float4v Z4 = {0.f, 0.f, 0.f, 0.f};

  for (int t = 0; t < kT; ++t) {
    // p B-fragments (k=64..95 region; zero on q>=2)
    short8 zph, zpl;
    {
      unsigned int hw[4], lw[4];
#pragma unroll
      for (int u2 = 0; u2 < 4; ++u2) sp2(pcur[2 * u2], pcur[2 * u2 + 1], hw[u2], lw[u2]);
      zph = mk8(hw[0], hw[1], hw[2], hw[3]);
      zpl = mk8(lw[0], lw[1], lw[2], lw[3]);
    }
    // step-invariant p-term (+bias0) for this wave's two tiles
    float4v psum[2];
#pragma unroll
    for (int u = 0; u < 2; ++u) {
      float4v s = MFMA(wp[u][0], zph, b0v[u]);
      s = MFMA(wp[u][0], zpl, s);
      s = MFMA(wp[u][1], zph, s);
      psum[u] = s;
    }
    // prefetch p(t+1)
    float pnx[8];
#pragma unroll
    for (int j = 0; j < 8; ++j) pnx[j] = 0.f;
    if (q < 2 && t + 1 < kT) {
#pragma unroll
      for (int j = 0; j < 8; ++j) pnx[j] = prow[j * kT + (t + 1)];
    }

    float d1v[4];
#pragma unroll
    for (int ev = 0; ev < 2; ++ev) {
      // ---- L0: read z B-frags, MFMA vs AGPR weights ----
      short8 zfh0 = RDZ(zhp, 0), zfh1 = RDZ(zhp, 1);
      short8 zfl0 = RDZ(zlp, 0), zfl1 = RDZ(zlp, 1);
#pragma unroll
      for (int u = 0; u < 2; ++u) {
        float4v acA = MFMA(wz[u][0], zfh0, psum[u]);
        acA = MFMA(wz[u][1], zfh1, acA);
        float4v acB = MFMA(wz[u][2], zfh0, Z4);
        acB = MFMA(wz[u][3], zfh1, acB);
        acB = MFMA(wz[u][0], zfl0, acB);
        acB = MFMA(wz[u][1], zfl1, acB);
        float4v a = acA + acB;
        unsigned int w0p2 = pk_bf16(fast_tanh(a[0]), fast_tanh(a[1]));
        unsigned int w1p2 = pk_bf16(fast_tanh(a[2]), fast_tanh(a[3]));
        *(uint2v*)&h0p[u ? hwi1 : hwi0] = (uint2v){w0p2, w1p2};
      }
      __syncthreads();
      // ---- L1 ----
      short8 h0f0 = RDH(h0p, 0), h0f1 = RDH(h0p, 1);
      short8 h0f2 = RDH(h0p, 2), h0f3 = RDH(h0p, 3);
#pragma unroll
      for (int u = 0; u < 2; ++u) {
        float4v acA = MFMA(w1f[u][0], h0f0, b1v[u]);
        acA = MFMA(w1f[u][1], h0f1, acA);
        float4v acB = MFMA(w1f[u][2], h0f2, Z4);
        acB = MFMA(w1f[u][3], h0f3, acB);
        float4v acC = MFMA(w1f[u][4], h0f0, Z4);
        acC = MFMA(w1f[u][5], h0f1, acC);
        float4v acD = MFMA(w1f[u][6], h0f2, Z4);
        acD = MFMA(w1f[u][7], h0f3, acD);
        float4v a = (acA + acB) + (acC + acD);
        unsigned int w0p2 = pk_bf16(fast_tanh(a[0]), fast_tanh(a[1]));
        unsigned int w1p2 = pk_bf16(fast_tanh(a[2]), fast_tanh(a[3]));
        *(uint2v*)&h1p[u ? hwi1 : hwi0] = (uint2v){w0p2, w1p2};
      }
      __syncthreads();
      // ---- L2 (one tile per wave) ----
      short8 h1f0 = RDH(h1p, 0), h1f1 = RDH(h1p, 1);
      short8 h1f2 = RDH(h1p, 2), h1f3 = RDH(h1p, 3);
      float4v acA = MFMA(w2f[0], h1f0, b2v);
      acA = MFMA(w2f[1], h1f1, acA);
      float4v acB = MFMA(w2f[2], h1f2, Z4);
      acB = MFMA(w2f[3], h1f3, acB);
      float4v acC = MFMA(w2f[4], h1f0, Z4);
      acC = MFMA(w2f[5], h1f1, acC);
      float4v acD = MFMA(w2f[6], h1f2, Z4);
      acD = MFMA(w2f[7], h1f3, acD);
      float4v a2v = (acA + acB) + (acC + acD);

      // ---- Heun update (lane-local, 4 dims) + z exchange ----
      if (ev == 0) {
        float xi[4];
#pragma unroll
        for (int r = 0; r < 4; ++r) {
          d1v[r] = a2v[r];
          xi[r] = stv[r] + a2v[r];  // dt = 1
        }
        unsigned int hw0, lw0, hw1, lw1;
        sp2(xi[0], xi[1], hw0, lw0);
        sp2(xi[2], xi[3], hw1, lw1);
        *(uint2v*)&zhp[zwi] = (uint2v){hw0, hw1};
        *(uint2v*)&zlp[zwi] = (uint2v){lw0, lw1};
      } else {
#pragma unroll
        for (int r = 0; r < 4; ++r) orow[r * kT + t] = stv[r];  // emit PREV state
#pragma unroll
        for (int r = 0; r < 4; ++r) stv[r] = stv[r] + 0.5f * (a2v[r] + d1v[r]);
        unsigned int hw0, lw0, hw1, lw1;
        sp2(stv[0], stv[1], hw0, lw0);
        sp2(stv[2], stv[3], hw1, lw1);
        *(uint2v*)&zhp[zwi] = (uint2v){hw0, hw1};
        *(uint2v*)&zlp[zwi] = (uint2v){lw0, lw1};
      }
      __syncthreads();
    }
#pragma unroll
    for (int j = 0; j < 8; ++j) pcur[j] = pnx[j];
  }
#undef RDH
#undef RDZ
}

}  // namespace

extern "C" void kernel_launch(void* const* d_in, const int* in_sizes, int n_in,
                              void* d_out, int out_size, void* d_ws, size_t ws_size,
                              hipStream_t stream) {
  const float* xg = (const float*)d_in[0];   // x [512,64,500]
  const float* pg = (const float*)d_in[1];   // p [512,16,500]
  // d_in[2] = i_ext (unused by Simple_MLP)
  const float* w0g = (const float*)d_in[3];  // W0 [80,128]
  const float* b0g = (const float*)d_in[4];  // b0 [128]
  const float* w1g = (const float*)d_in[5];  // W1 [128,128]
  const float* b1g = (const float*)d_in[6];  // b1 [128]
  const float* w2g = (const float*)d_in[7];  // W2 [128,64]
  const float* b2g = (const float*)d_in[8];  // b2 [64]
  float* outg = (float*)d_out;               // [512,64,500] fp32

  hipLaunchKernelGGL(node_kernel, dim3(kBlocks), dim3(kThreads), 0, stream,
                     xg, pg, w0g, b0g, w1g, b1g, w2g, b2g, outg);
}

// Round 11
// 1364.260 us; speedup vs baseline: 2.9105x; 1.0192x over previous
//
#include <hip/hip_runtime.h>

namespace {

constexpr int kB = 512, kD = 64, kP = 16, kT = 500, kH = 128;
constexpr int kRows = 16;            // batch rows per block (MFMA N=16)
constexpr int kBlocks = kB / kRows;  // 32
constexpr int kThreads = 256;        // 4 waves: tiles split across waves

typedef __attribute__((ext_vector_type(8))) short short8;
typedef __attribute__((ext_vector_type(4))) float float4v;
typedef __attribute__((ext_vector_type(2))) unsigned int uint2v;

__device__ __forceinline__ float bf2f(unsigned short u) {
  union { unsigned int i; float f; } v;
  v.i = ((unsigned int)u) << 16;
  return v.f;
}
__device__ __forceinline__ unsigned short f2bf(float f) {  // RNE
  union { float f; unsigned int i; } v;
  v.f = f;
  return (unsigned short)((v.i + 0x7FFFu + ((v.i >> 16) & 1u)) >> 16);
}
__device__ __forceinline__ void split_bf(float x, unsigned short& hi, unsigned short& lo) {
  hi = f2bf(x);
  lo = f2bf(x - bf2f(hi));
}
#if __has_builtin(__builtin_amdgcn_cvt_pk_bf16_f32)
__device__ __forceinline__ unsigned int pk_bf16(float a, float b) {
  auto v = __builtin_amdgcn_cvt_pk_bf16_f32(a, b);
  unsigned int u;
  __builtin_memcpy(&u, &v, 4);
  return u;
}
#else
__device__ __forceinline__ unsigned int pk_bf16(float a, float b) {
  return (unsigned int)f2bf(a) | ((unsigned int)f2bf(b) << 16);
}
#endif
// split pair (a,b) into packed bf16 hi word + lo word
__device__ __forceinline__ void sp2(float a, float b, unsigned int& hw, unsigned int& lw) {
  unsigned int uh = pk_bf16(a, b);
  float ah, bh;
  { unsigned int t1 = uh << 16; __builtin_memcpy(&ah, &t1, 4); }
  { unsigned int t2 = uh & 0xFFFF0000u; __builtin_memcpy(&bh, &t2, 4); }
  hw = uh;
  lw = pk_bf16(a - ah, b - bh);
}
__device__ __forceinline__ short8 mk8(unsigned int a, unsigned int b, unsigned int c,
                                      unsigned int d) {
  union { unsigned int w[4]; short8 s; } u;
  u.w[0] = a; u.w[1] = b; u.w[2] = c; u.w[3] = d;
  return u.s;
}
__device__ __forceinline__ float fast_tanh(float x) {
  float e = __builtin_amdgcn_exp2f(x * 2.885390081777927f);  // 2*log2(e)
  return 1.0f - 2.0f * __builtin_amdgcn_rcpf(e + 1.0f);
}

#define MFMA(a, b, c) __builtin_amdgcn_mfma_f32_16x16x32_bf16((a), (b), (c), 0, 0, 0)

// 4-wave transposed-MFMA hybrid (round 10 base, 1288us profiled, no spill).
// A = W^T tile (ALL weights AGPR-resident: 36 frags = 144 regs per wave),
// B = activations^T (batch row = lane&15), D[hidden][row]. Tile T covers
// hidden cols n(T,m) = 32*(T>>1) + 8*(m>>2) + 4*(T&1) + (m&3), m = quad*4+r.
// Wave w owns L0/L1 tiles {2w,2w+1}, L2 tile {w}. Activations exchanged via
// tiny XOR-swizzled LDS planes in absolute (row,col) coordinates.
// This round's cuts (counter-driven): (1) 8-step LDS yb output burst -- the
// per-step scattered global stores no longer drain at every barrier;
// (2) float4 p prefetch every 4 steps + static shift-register front;
// (3) psum(t+1) computed inside eval-1 (MFMA pipe overlaps Heun VALU);
// (4) L0/psum chains split to depth 2. Product set unchanged.
__global__ __launch_bounds__(kThreads, 1) void node_kernel(
    const float* __restrict__ xg, const float* __restrict__ pg,
    const float* __restrict__ w0g, const float* __restrict__ b0g,
    const float* __restrict__ w1g, const float* __restrict__ b1g,
    const float* __restrict__ w2g, const float* __restrict__ b2g,
    float* __restrict__ outg) {
  // Exchange planes (bf16), col XOR-swizzled by ((l15&7)<<3) shorts.
  __shared__ __align__(16) unsigned short h0p[16 * 128];
  __shared__ __align__(16) unsigned short h1p[16 * 128];
  __shared__ __align__(16) unsigned short zhp[16 * 64];
  __shared__ __align__(16) unsigned short zlp[16 * 64];
  __shared__ __align__(16) float yb[8][16 * 68];  // 8-step output staging (+4 pad/row)

  const int tid = threadIdx.x;
  const int wv = tid >> 6;  // wave 0..3
  const int lane = tid & 63;
  const int l15 = lane & 15;
  const int q = lane >> 4;
  const int brow = blockIdx.x * kRows;
  const int sw = (l15 & 7) << 3;  // plane col swizzle (short units)

  // ---- per-wave weight fragments -> AGPRs (36 frags = 144 regs) ----
  short8 wz[2][4], wp[2][2], w1f[2][8], w2f[8];
#pragma unroll
  for (int u = 0; u < 2; ++u) {
    const int T = 2 * wv + u;
    const int nW = 32 * (T >> 1) + 8 * (l15 >> 2) + 4 * (T & 1) + (l15 & 3);
#pragma unroll
    for (int kt = 0; kt < 2; ++kt) {
      short8 vh, vl;
#pragma unroll
      for (int j = 0; j < 8; ++j) {
        unsigned short hi, lo;
        split_bf(w0g[(kt * 32 + q * 8 + j) * kH + nW], hi, lo);
        vh[j] = (short)hi; vl[j] = (short)lo;
      }
      wz[u][kt] = vh; wz[u][2 + kt] = vl;
    }
    {
      short8 vh, vl;
#pragma unroll
      for (int j = 0; j < 8; ++j) {
        int k = 64 + q * 8 + j;
        unsigned short hi = 0, lo = 0;
        if (k < 80) split_bf(w0g[k * kH + nW], hi, lo);
        vh[j] = (short)hi; vl[j] = (short)lo;
      }
      wp[u][0] = vh; wp[u][1] = vl;
    }
#pragma unroll
    for (int kt = 0; kt < 4; ++kt) {
      short8 vh, vl;
#pragma unroll
      for (int j = 0; j < 8; ++j) {
        unsigned short hi, lo;
        split_bf(w1g[(kt * 32 + q * 8 + j) * kH + nW], hi, lo);
        vh[j] = (short)hi; vl[j] = (short)lo;
      }
      w1f[u][kt] = vh; w1f[u][4 + kt] = vl;
    }
  }
  {
    const int nW2 = 32 * (wv >> 1) + 8 * (l15 >> 2) + 4 * (wv & 1) + (l15 & 3);
#pragma unroll
    for (int kt = 0; kt < 4; ++kt) {
      short8 vh, vl;
#pragma unroll
      for (int j = 0; j < 8; ++j) {
        unsigned short hi, lo;
        split_bf(w2g[(kt * 32 + q * 8 + j) * kD + nW2], hi, lo);
        vh[j] = (short)hi; vl[j] = (short)lo;
      }
      w2f[kt] = vh; w2f[4 + kt] = vl;
    }
  }
#pragma unroll
  for (int u = 0; u < 2; ++u) {
    asm("" : "+a"(wz[u][0]), "+a"(wz[u][1]), "+a"(wz[u][2]), "+a"(wz[u][3]));
    asm("" : "+a"(wp[u][0]), "+a"(wp[u][1]));
    asm("" : "+a"(w1f[u][0]), "+a"(w1f[u][1]), "+a"(w1f[u][2]), "+a"(w1f[u][3]));
    asm("" : "+a"(w1f[u][4]), "+a"(w1f[u][5]), "+a"(w1f[u][6]), "+a"(w1f[u][7]));
  }
  asm("" : "+a"(w2f[0]), "+a"(w2f[1]), "+a"(w2f[2]), "+a"(w2f[3]));
  asm("" : "+a"(w2f[4]), "+a"(w2f[5]), "+a"(w2f[6]), "+a"(w2f[7]));

  // ---- biases in registers ----
  const int bqw = 32 * wv + 8 * q;
  float4v b0v[2] = {*(const float4v*)&b0g[bqw], *(const float4v*)&b0g[bqw + 4]};
  float4v b1v[2] = {*(const float4v*)&b1g[bqw], *(const float4v*)&b1g[bqw + 4]};
  const int n0out = 32 * (wv >> 1) + 8 * q + 4 * (wv & 1);  // L2 tile col base
  float4v b2v = *(const float4v*)&b2g[n0out];

  // ---- lane-local fp32 state: 4 dims (n0out + r), row l15 ----
  float stv[4];
#pragma unroll
  for (int r = 0; r < 4; ++r)
    stv[r] = xg[((size_t)(brow + l15) * kD + n0out + r) * kT];

  const float* prow = pg + ((size_t)(brow + l15) * kP + q * 8) * kT;  // q<2

  // p shift-register: pq[j] holds p for the next 4 consumed steps (front = [0]).
  float4v pq[8];
#pragma unroll
  for (int j = 0; j < 8; ++j) pq[j] = (float4v){0.f, 0.f, 0.f, 0.f};
  if (q < 2) {
#pragma unroll
    for (int j = 0; j < 8; ++j) pq[j] = *(const float4v*)&prow[j * kT];  // t=0..3
  }

  // plane addresses
  const int zwi = l15 * 64 + (n0out ^ sw);
  const int hwi0 = l15 * 128 + ((bqw) ^ sw);
  const int hwi1 = l15 * 128 + ((bqw + 4) ^ sw);
#define RDH(plane, kt) (*(const short8*)&plane[l15 * 128 + ((((kt)*32) + q * 8) ^ sw)])
#define RDZ(plane, kt) (*(const short8*)&plane[l15 * 64 + ((((kt)*32) + q * 8) ^ sw)])

  // ---- init z planes from state ----
  {
    unsigned int hw0, lw0, hw1, lw1;
    sp2(stv[0], stv[1], hw0, lw0);
    sp2(stv[2], stv[3], hw1, lw1);
    *(uint2v*)&zhp[zwi] = (uint2v){hw0, hw1};
    *(uint2v*)&zlp[zwi] = (uint2v){lw0, lw1};
  }
  __syncthreads();

  const float4v Z4 = {0.f, 0.f, 0.f, 0.f};

  // psum from pq fronts (depth-2 chains); shift-register advance.
  auto calc_psum = [&](float4v* ps) {
    unsigned int hw[4], lw[4];
#pragma unroll
    for (int u2 = 0; u2 < 4; ++u2) sp2(pq[2 * u2][0], pq[2 * u2 + 1][0], hw[u2], lw[u2]);
    short8 zph = mk8(hw[0], hw[1], hw[2], hw[3]);
    short8 zpl = mk8(lw[0], lw[1], lw[2], lw[3]);
#pragma unroll
    for (int u = 0; u < 2; ++u) {
      float4v s1 = MFMA(wp[u][0], zph, b0v[u]);
      float4v s2 = MFMA(wp[u][1], zph, Z4);
      s2 = MFMA(wp[u][0], zpl, s2);
      ps[u] = s1 + s2;
    }
  };
  auto shiftpq = [&]() {
#pragma unroll
    for (int j = 0; j < 8; ++j) {
      float4v t4 = pq[j];
      pq[j] = (float4v){t4[1], t4[2], t4[3], t4[3]};
    }
  };

  float4v psum[2];
  calc_psum(psum);  // t = 0
  shiftpq();

  for (int t = 0; t < kT; ++t) {
    // reload p shift-register every 4 steps (covers t+1..t+4; 16B-aligned)
    if (((t & 3) == 3) && (t + 4 < kT) && q < 2) {
#pragma unroll
      for (int j = 0; j < 8; ++j) pq[j] = *(const float4v*)&prow[j * kT + t + 1];
    }
    // burst previous 8-step output tile (stores drain under ev0 compute)
    if ((t & 7) == 0 && t) {
      const int t0 = t - 8;
#pragma unroll
      for (int k2 = 0; k2 < 4; ++k2) {
        int idx = tid + k2 * kThreads;
        int rr = idx >> 6, cc = idx & 63;
        float v[8];
#pragma unroll
        for (int s = 0; s < 8; ++s) v[s] = yb[s][rr * 68 + cc];
        float* dst = outg + ((size_t)(brow + rr) * kD + cc) * kT + t0;
        *(float4v*)dst = (float4v){v[0], v[1], v[2], v[3]};
        *(float4v*)(dst + 4) = (float4v){v[4], v[5], v[6], v[7]};
      }
    }

    float d1v[4];
#pragma unroll
    for (int ev = 0; ev < 2; ++ev) {
      // ---- L0: z B-frags vs AGPR weights; three depth-2 chains/tile ----
      short8 zfh0 = RDZ(zhp, 0), zfh1 = RDZ(zhp, 1);
      short8 zfl0 = RDZ(zlp, 0), zfl1 = RDZ(zlp, 1);
#pragma unroll
      for (int u = 0; u < 2; ++u) {
        float4v acA = MFMA(wz[u][0], zfh0, psum[u]);
        acA = MFMA(wz[u][1], zfh1, acA);
        float4v acB = MFMA(wz[u][2], zfh0, Z4);
        acB = MFMA(wz[u][3], zfh1, acB);
        float4v acC = MFMA(wz[u][0], zfl0, Z4);
        acC = MFMA(wz[u][1], zfl1, acC);
        float4v a = acA + (acB + acC);
        unsigned int w0p2 = pk_bf16(fast_tanh(a[0]), fast_tanh(a[1]));
        unsigned int w1p2 = pk_bf16(fast_tanh(a[2]), fast_tanh(a[3]));
        *(uint2v*)&h0p[u ? hwi1 : hwi0] = (uint2v){w0p2, w1p2};
      }
      __syncthreads();
      // ---- L1 ----
      short8 h0f0 = RDH(h0p, 0), h0f1 = RDH(h0p, 1);
      short8 h0f2 = RDH(h0p, 2), h0f3 = RDH(h0p, 3);
#pragma unroll
      for (int u = 0; u < 2; ++u) {
        float4v acA = MFMA(w1f[u][0], h0f0, b1v[u]);
        acA = MFMA(w1f[u][1], h0f1, acA);
        float4v acB = MFMA(w1f[u][2], h0f2, Z4);
        acB = MFMA(w1f[u][3], h0f3, acB);
        float4v acC = MFMA(w1f[u][4], h0f0, Z4);
        acC = MFMA(w1f[u][5], h0f1, acC);
        float4v acD = MFMA(w1f[u][6], h0f2, Z4);
        acD = MFMA(w1f[u][7], h0f3, acD);
        float4v a = (acA + acB) + (acC + acD);
        unsigned int w0p2 = pk_bf16(fast_tanh(a[0]), fast_tanh(a[1]));
        unsigned int w1p2 = pk_bf16(fast_tanh(a[2]), fast_tanh(a[3]));
        *(uint2v*)&h1p[u ? hwi1 : hwi0] = (uint2v){w0p2, w1p2};
      }
      __syncthreads();
      // ---- L2 (one tile per wave) ----
      short8 h1f0 = RDH(h1p, 0), h1f1 = RDH(h1p, 1);
      short8 h1f2 = RDH(h1p, 2), h1f3 = RDH(h1p, 3);
      float4v acA = MFMA(w2f[0], h1f0, b2v);
      acA = MFMA(w2f[1], h1f1, acA);
      float4v acB = MFMA(w2f[2], h1f2, Z4);
      acB = MFMA(w2f[3], h1f3, acB);
      float4v acC = MFMA(w2f[4], h1f0, Z4);
      acC = MFMA(w2f[5], h1f1, acC);
      float4v acD = MFMA(w2f[6], h1f2, Z4);
      acD = MFMA(w2f[7], h1f3, acD);
      float4v a2v = (acA + acB) + (acC + acD);

      // ---- Heun update (lane-local) + z exchange ----
      if (ev == 0) {
        float xi[4];
#pragma unroll
        for (int r = 0; r < 4; ++r) {
          d1v[r] = a2v[r];
          xi[r] = stv[r] + a2v[r];  // dt = 1
        }
        unsigned int hw0, lw0, hw1, lw1;
        sp2(xi[0], xi[1], hw0, lw0);
        sp2(xi[2], xi[3], hw1, lw1);
        *(uint2v*)&zhp[zwi] = (uint2v){hw0, hw1};
        *(uint2v*)&zlp[zwi] = (uint2v){lw0, lw1};
      } else {
        // psum for t+1: independent MFMA work overlapping the Heun VALU
        float4v psumN[2];
        calc_psum(psumN);
        shiftpq();
#pragma unroll
        for (int r = 0; r < 4; ++r)
          yb[t & 7][l15 * 68 + n0out + r] = stv[r];  // emit PREV state
#pragma unroll
        for (int r = 0; r < 4; ++r) stv[r] = stv[r] + 0.5f * (a2v[r] + d1v[r]);
        unsigned int hw0, lw0, hw1, lw1;
        sp2(stv[0], stv[1], hw0, lw0);
        sp2(stv[2], stv[3], hw1, lw1);
        *(uint2v*)&zhp[zwi] = (uint2v){hw0, hw1};
        *(uint2v*)&zlp[zwi] = (uint2v){lw0, lw1};
        psum[0] = psumN[0];
        psum[1] = psumN[1];
      }
      __syncthreads();
    }
  }
  // tail flush: t = 496..499 (slots 0..3)
  __syncthreads();
  {
    const int t0 = (kT / 8) * 8;  // 496
#pragma unroll
    for (int k2 = 0; k2 < 4; ++k2) {
      int idx = tid + k2 * kThreads;
      int rr = idx >> 6, cc = idx & 63;
      float v[4];
#pragma unroll
      for (int s = 0; s < 4; ++s) v[s] = yb[s][rr * 68 + cc];
      float* dst = outg + ((size_t)(brow + rr) * kD + cc) * kT + t0;
      *(float4v*)dst = (float4v){v[0], v[1], v[2], v[3]};
    }
  }
#undef RDH
#undef RDZ
}

}  // namespace

extern "C" void kernel_launch(void* const* d_in, const int* in_sizes, int n_in,
                              void* d_out, int out_size, void* d_ws, size_t ws_size,
                              hipStream_t stream) {
  const float* xg = (const float*)d_in[0];   // x [512,64,500]
  const float* pg = (const float*)d_in[1];   // p [512,16,500]
  // d_in[2] = i_ext (unused by Simple_MLP)
  const float* w0g = (const float*)d_in[3];  // W0 [80,128]
  const float* b0g = (const float*)d_in[4];  // b0 [128]
  const float* w1g = (const float*)d_in[5];  // W1 [128,128]
  const float* b1g = (const float*)d_in[6];  // b1 [128]
  const float* w2g = (const float*)d_in[7];  // W2 [128,64]
  const float* b2g = (const float*)d_in[8];  // b2 [64]
  float* outg = (float*)d_out;               // [512,64,500] fp32

  hipLaunchKernelGGL(node_kernel, dim3(kBlocks), dim3(kThreads), 0, stream,
                     xg, pg, w0g, b0g, w1g, b1g, w2g, b2g, outg);
}